// Round 1
// baseline (392.058 us; speedup 1.0000x reference)
//
#include <hip/hip_runtime.h>

// OnlineEmbedding: out[b,h,:] = table[ids[b,h], :]
// ids: [4096*200] int32 (values < 1e6), table: [1e6, 64] fp32, out: [4096*200, 64] fp32.
// Each row is 64 floats = 16 float4. Assign 16 consecutive lanes per row:
// lanes 0..15 -> row r chunks 0..15 (contiguous 256B read from table, contiguous write).
__global__ __launch_bounds__(256) void OnlineEmbedding_gather(
    const int* __restrict__ ids,
    const float4* __restrict__ table,
    float4* __restrict__ out,
    int n_ids)
{
    int t = blockIdx.x * blockDim.x + threadIdx.x;
    int row = t >> 4;         // which lookup
    int c   = t & 15;         // which 16B chunk of the 256B embedding row
    if (row < n_ids) {
        int id = ids[row];
        out[(size_t)row * 16 + c] = table[(size_t)id * 16 + c];
    }
}

extern "C" void kernel_launch(void* const* d_in, const int* in_sizes, int n_in,
                              void* d_out, int out_size, void* d_ws, size_t ws_size,
                              hipStream_t stream) {
    const int*    ids   = (const int*)d_in[0];
    const float4* table = (const float4*)d_in[1];
    float4*       out   = (float4*)d_out;

    int n_ids = in_sizes[0];              // 4096*200 = 819200
    int total_threads = n_ids * 16;       // 16 lanes per embedding row
    int block = 256;
    int grid  = (total_threads + block - 1) / block;

    OnlineEmbedding_gather<<<grid, block, 0, stream>>>(ids, table, out, n_ids);
}